// Round 8
// baseline (201.256 us; speedup 1.0000x reference)
//
#include <hip/hip_runtime.h>
#include <stdint.h>

// Problem constants
#define K_DIM   2048      // IN_DIM
#define NN      2047      // N_NODES
#define NPAD    2048      // padded node dim
#define BATCH   16384
#define ODIM    10
#define IOFF    (128 * 2048)   // +128 rows (A) / +128 cols (B) in elements
#define HOFF    (256 * 2048)   // +256 rows: second output tile of this wg

typedef __attribute__((ext_vector_type(8))) short  bf16x8;
typedef __attribute__((ext_vector_type(4))) float  f32x4;

static __device__ __forceinline__ unsigned short f2bf(float f) {
    union { float f; unsigned int u; } c; c.f = f;
    unsigned int u = c.u;
    return (unsigned short)((u + 0x7fffu + ((u >> 16) & 1u)) >> 16);
}
static __device__ __forceinline__ float bf2f(unsigned short h) {
    union { unsigned int u; float f; } c; c.u = ((unsigned int)h) << 16;
    return c.f;
}

// ---------------- fused fp32 -> bf16 conversion: in_x and padded W1 ----------------
__global__ __launch_bounds__(256) void cvt_all(const float* __restrict__ xs,
                                               const float* __restrict__ ws,
                                               unsigned short* __restrict__ dx,
                                               unsigned short* __restrict__ dw) {
    int b = blockIdx.x;
    union { unsigned short h[8]; uint4 v; } o;
    if (b < 16384) {
        int i = b * 256 + threadIdx.x;
        const float4* s = (const float4*)xs + (size_t)i * 2;
        float4 a = s[0], c = s[1];
        o.h[0] = f2bf(a.x); o.h[1] = f2bf(a.y); o.h[2] = f2bf(a.z); o.h[3] = f2bf(a.w);
        o.h[4] = f2bf(c.x); o.h[5] = f2bf(c.y); o.h[6] = f2bf(c.z); o.h[7] = f2bf(c.w);
        *((uint4*)dx + i) = o.v;
    } else {
        int i = (b - 16384) * 256 + threadIdx.x;
        size_t e = (size_t)i * 8;
        int row = (int)(e >> 11);
        if (row < NN) {
            const float4* s = (const float4*)(ws + e);
            float4 a = s[0], c = s[1];
            o.h[0] = f2bf(a.x); o.h[1] = f2bf(a.y); o.h[2] = f2bf(a.z); o.h[3] = f2bf(a.w);
            o.h[4] = f2bf(c.x); o.h[5] = f2bf(c.y); o.h[6] = f2bf(c.z); o.h[7] = f2bf(c.w);
        } else {
            o.v = make_uint4(0u, 0u, 0u, 0u);
        }
        *((uint4*)dw + i) = o.v;
    }
}

// ---------------- 256x256 bf16 MFMA GEMM, fused 2 output row-tiles per wg ----------------
// R7 phase structure verbatim; grid 256 (1 wg/CU, single prologue); 64 continuous K-tiles
// (0-31 -> rowBase, 32-63 -> rowBase+256, same colBase; B panels re-staged L2-hot);
// mid-kernel epilogue at the seam; unroll-4 folds kt into load offset fields.
__global__ __launch_bounds__(512, 1) void gemm8(const unsigned short* __restrict__ A,
                                                const unsigned short* __restrict__ B,
                                                const float* __restrict__ bias,
                                                unsigned short* __restrict__ X) {
    __shared__ char lds[131072];   // 2 buf x {A0,A1,B0,B1} x 16KiB

    const int t0   = threadIdx.x;
    const int w    = t0 >> 6;
    const int lane = t0 & 63;
    const int wm = w >> 2, wn = w & 3;     // wave -> 128x64 output block
    const int lr = lane & 15, lk = lane >> 4;
    const int xmask = (lr & 7) << 4;       // read-side swizzle

    // XCD-aware swizzle: 256 wgs, 32 per XCD
    int bid = blockIdx.x;
    int swz = (bid & 7) * 32 + (bid >> 3);
    const int rowBase = (swz >> 3) * 512;  // 32 row-pairs of 256-tiles
    const int colBase = (swz & 7) * 256;   // 8 col-tiles

    // staging source pointers (pre-swizzled global addresses); i=1 = +IOFF elems
    const int li = lane >> 3;   // row-within-8
    const int lg = lane & 7;    // 16B granule
    const unsigned short* sAlo[2];
    const unsigned short* sAhi[2];
    const unsigned short* sB[2];
    {
        int rho = w * 8 + li;                              // 0..63
        int gc  = (lg ^ (rho & 7)) * 8;                    // swizzled k-granule
#pragma unroll
        for (int h = 0; h < 2; ++h) {
            sAlo[h] = A + (size_t)(rowBase + h * 64 + rho) * K_DIM + gc;
            sAhi[h] = sAlo[h] + HOFF;
            sB[h]   = B + (size_t)(colBase + (rho >> 5) * 64 + h * 32 + (rho & 31)) * K_DIM + gc;
        }
    }

#define AS1 __attribute__((address_space(1)))
#define AS3 __attribute__((address_space(3)))
#define STAGE_(src, dstoff) \
    __builtin_amdgcn_global_load_lds((const AS1 void*)(src), \
        (AS3 void*)(lds + (dstoff) + w * 1024), 16, 0, 0)
#define STAGE_A(PS, hh, kt, p) do { const unsigned short* _s = PS[hh] + (kt) * 64; \
    const int _d = (p) * 65536 + (hh) * 16384; \
    STAGE_(_s, _d); STAGE_(_s + IOFF, _d + 8192); } while (0)
#define STAGE_B(gg, kt, p) do { const unsigned short* _s = sB[gg] + (kt) * 64; \
    const int _d = (p) * 65536 + 32768 + (gg) * 16384; \
    STAGE_(_s, _d); STAGE_(_s + IOFF, _d + 8192); } while (0)

#define LDSA(bo, hh, mm, ks) (*(const bf16x8*)(lds + (bo) + (hh) * 16384 + \
        (wm * 64 + (mm) * 16 + lr) * 128 + (((ks) * 64 + lk * 16) ^ xmask)))
#define LDSB(bo, gg, nn, ks) (*(const bf16x8*)(lds + (bo) + 32768 + (gg) * 16384 + \
        (wn * 32 + (nn) * 16 + lr) * 128 + (((ks) * 64 + lk * 16) ^ xmask)))

#define BAR()   __builtin_amdgcn_s_barrier()
#define VM8()   asm volatile("s_waitcnt vmcnt(8)" ::: "memory")
#define VM10()  asm volatile("s_waitcnt vmcnt(10)" ::: "memory")
#define PRIO1() __builtin_amdgcn_s_setprio(1)
#define PRIO0() __builtin_amdgcn_s_setprio(0)

    f32x4 acc[8][4];
#pragma unroll
    for (int m = 0; m < 8; ++m)
#pragma unroll
        for (int n = 0; n < 4; ++n) acc[m][n] = (f32x4)0.f;

    bf16x8 aF[4][2], bF1[2][2], bF0a[2][2], bF0b[2][2];

#define RD8A(bo, hh) do { \
    _Pragma("unroll") for (int m = 0; m < 4; ++m) { \
        aF[m][0] = LDSA(bo, hh, m, 0); aF[m][1] = LDSA(bo, hh, m, 1); } } while (0)
#define RD4B(dst, bo, gg) do { \
    _Pragma("unroll") for (int n = 0; n < 2; ++n) { \
        dst[n][0] = LDSB(bo, gg, n, 0); dst[n][1] = LDSB(bo, gg, n, 1); } } while (0)

#define MFMA8(MB, NB, BF) do { \
    _Pragma("unroll") for (int m = 0; m < 4; ++m) \
    _Pragma("unroll") for (int n = 0; n < 2; ++n) \
    _Pragma("unroll") for (int ks = 0; ks < 2; ++ks) \
        acc[(MB) + m][(NB) + n] = __builtin_amdgcn_mfma_f32_16x16x32_bf16( \
            aF[m][ks], BF[n][ks], acc[(MB) + m][(NB) + n], 0, 0, 0); } while (0)

    // hoisted bias (colBase fixed for both output tiles)
    float bb[4];
#pragma unroll
    for (int ni = 0; ni < 4; ++ni) {
        int col = colBase + wn * 64 + (ni >> 1) * 32 + (ni & 1) * 16 + lr;
        bb[ni] = (col < NN) ? bias[col] : 0.f;
    }

#define EPI(RB) do { \
    _Pragma("unroll") for (int mi = 0; mi < 8; ++mi) { \
        int row = (RB) + wm * 128 + (mi >> 2) * 64 + (mi & 3) * 16 + lk * 4; \
        _Pragma("unroll") for (int j = 0; j < 4; ++j) { \
            unsigned short* xr = X + (size_t)(row + j) * NPAD + colBase + wn * 64 + lr; \
            _Pragma("unroll") for (int ni = 0; ni < 4; ++ni) \
                xr[(ni >> 1) * 32 + (ni & 1) * 16] = f2bf(acc[mi][ni][j] + bb[ni]); \
        } } } while (0)

    // ---- prologue: tile0 full + tile1 {A0,B0,B1,A1} = 8 stage-pairs (LO pointer set) ----
    STAGE_A(sAlo, 0, 0, 0); STAGE_A(sAlo, 1, 0, 0); STAGE_B(0, 0, 0); STAGE_B(1, 0, 0);
    STAGE_A(sAlo, 0, 1, 1); STAGE_B(0, 1, 1); STAGE_B(1, 1, 1); STAGE_A(sAlo, 1, 1, 1);
    VM8(); BAR();                     // drains tile0's 4 pairs
    RD4B(bF0a, 0, 0);                 // pre-read B0(tile0)

    // Phase schedule identical to R7; S1 = pointer set for P1's A1(T+1) stage,
    // S0 = pointer set for P2's A0(T+2) stage.
#define TILE(T, PAR, CUR, NXT, S1, S0) do { \
    const int _bo = (PAR) * 65536, _bp = ((PAR) ^ 1) * 65536; \
    const int _k1 = ((T) + 1) & 31, _k2 = ((T) + 2) & 31; \
    STAGE_A(S1, 1, _k1, (PAR) ^ 1); \
    RD8A(_bo, 0); \
    PRIO1(); MFMA8(0, 0, CUR); PRIO0(); BAR(); \
    STAGE_A(S0, 0, _k2, (PAR)); \
    RD4B(bF1, _bo, 1); \
    PRIO1(); MFMA8(0, 2, bF1); PRIO0(); VM10(); BAR(); \
    STAGE_B(0, _k2, (PAR)); \
    RD8A(_bo, 1); \
    PRIO1(); MFMA8(4, 2, bF1); PRIO0(); VM8(); BAR(); \
    STAGE_B(1, _k2, (PAR)); \
    RD4B(NXT, _bp, 0); \
    PRIO1(); MFMA8(4, 0, CUR); PRIO0(); VM8(); BAR(); \
} while (0)

    // ---- output tile 0: K-tiles 0..31 (tiles 30/31 pre-stage the second output tile) ----
#pragma unroll 4
    for (int tp = 0; tp < 15; ++tp) {
        TILE(tp * 2,     0, bF0a, bF0b, sAlo, sAlo);
        TILE(tp * 2 + 1, 1, bF0b, bF0a, sAlo, sAlo);
    }
    TILE(30, 0, bF0a, bF0b, sAlo, sAhi);   // A0(32) comes from the HI tile
    TILE(31, 1, bF0b, bF0a, sAhi, sAhi);   // A1(32) HI
    EPI(rowBase);
#pragma unroll
    for (int m = 0; m < 8; ++m)
#pragma unroll
        for (int n = 0; n < 4; ++n) acc[m][n] = (f32x4)0.f;

    // ---- output tile 1: K-tiles 32..63 (tail stages wrap harmlessly) ----
#pragma unroll 4
    for (int tp = 0; tp < 16; ++tp) {
        TILE(32 + tp * 2, 0, bF0a, bF0b, sAhi, sAhi);
        TILE(33 + tp * 2, 1, bF0b, bF0a, sAhi, sAhi);
    }
    EPI(rowBase + 256);
}

// ---------------- tree kernel: out[b,a] = S_abs[b] - min_{leaf≡a mod 10} pathPenalty ----------------
__global__ __launch_bounds__(256) void tree_kernel(const unsigned short* __restrict__ X,
                                                   float* __restrict__ out) {
    __shared__ float xs[4][2048];
    __shared__ float cm[4][64][ODIM];
    const int w    = threadIdx.x >> 6;
    const int lane = threadIdx.x & 63;
    const int row  = blockIdx.x * 4 + w;
    const unsigned short* xr = X + (size_t)row * NPAD;

#pragma unroll
    for (int i = 0; i < 4; ++i) {
        int base = i * 512 + lane * 8;
        uint4 v = *(const uint4*)(xr + base);
        const unsigned short* h = (const unsigned short*)&v;
#pragma unroll
        for (int j = 0; j < 8; ++j) xs[w][base + j] = bf2f(h[j]);
    }
    __syncthreads();

    float sabs = 0.f;
#pragma unroll
    for (int i = 0; i < 32; ++i) sabs += fabsf(xs[w][lane + i * 64]);
#pragma unroll
    for (int d = 1; d < 64; d <<= 1) sabs += __shfl_xor(sabs, d, 64);

    const int L = lane;
    float bp = 0.f;
#pragma unroll
    for (int l = 0; l <= 5; ++l) {
        float v = xs[w][(1 << l) - 1 + (L >> (6 - l))];
        bp += ((L >> (5 - l)) & 1) ? fmaxf(v, 0.f) : fmaxf(-v, 0.f);
    }
    float p2[2], p4[4], p8[8], p16[16], p32[32];
    {
        float v = xs[w][63 + L];
        p2[0] = bp + fmaxf(-v, 0.f);
        p2[1] = bp + fmaxf(v, 0.f);
    }
#pragma unroll
    for (int c = 0; c < 2; ++c) {
        float v = xs[w][127 + 2 * L + c];
        p4[2 * c]     = p2[c] + fmaxf(-v, 0.f);
        p4[2 * c + 1] = p2[c] + fmaxf(v, 0.f);
    }
#pragma unroll
    for (int c = 0; c < 4; ++c) {
        float v = xs[w][255 + 4 * L + c];
        p8[2 * c]     = p4[c] + fmaxf(-v, 0.f);
        p8[2 * c + 1] = p4[c] + fmaxf(v, 0.f);
    }
#pragma unroll
    for (int c = 0; c < 8; ++c) {
        float v = xs[w][511 + 8 * L + c];
        p16[2 * c]     = p8[c] + fmaxf(-v, 0.f);
        p16[2 * c + 1] = p8[c] + fmaxf(v, 0.f);
    }
#pragma unroll
    for (int c = 0; c < 16; ++c) {
        float v = xs[w][1023 + 16 * L + c];
        p32[2 * c]     = p16[c] + fmaxf(-v, 0.f);
        p32[2 * c + 1] = p16[c] + fmaxf(v, 0.f);
    }

    float m[ODIM];
#pragma unroll
    for (int r = 0; r < ODIM; ++r) m[r] = 1e30f;
#pragma unroll
    for (int tt = 0; tt < 32; ++tt) m[tt % ODIM] = fminf(m[tt % ODIM], p32[tt]);

    int base_mod = (L * 32) % ODIM;
#pragma unroll
    for (int r = 0; r < ODIM; ++r) {
        int a = base_mod + r; if (a >= ODIM) a -= ODIM;
        cm[w][L][a] = m[r];
    }
    __syncthreads();

    if (lane < ODIM) {
        float mn = 1e30f;
        for (int l2 = 0; l2 < 64; ++l2) mn = fminf(mn, cm[w][l2][lane]);
        out[(size_t)row * ODIM + lane] = sabs - mn;
    }
}

extern "C" void kernel_launch(void* const* d_in, const int* in_sizes, int n_in,
                              void* d_out, int out_size, void* d_ws, size_t ws_size,
                              hipStream_t stream) {
    const float* in_x = (const float*)d_in[0];
    const float* W1   = (const float*)d_in[1];
    const float* b1   = (const float*)d_in[2];

    unsigned short* Abf = (unsigned short*)d_ws;                      // 16384*2048 bf16
    unsigned short* Wbf = Abf + (size_t)BATCH * K_DIM;                // 2048*2048 bf16
    unsigned short* Xbf = Wbf + (size_t)NPAD * K_DIM;                 // 16384*2048 bf16
    float* out = (float*)d_out;

    cvt_all<<<18432, 256, 0, stream>>>(in_x, W1, Abf, Wbf);
    gemm8<<<256, 512, 0, stream>>>(Abf, Wbf, b1, Xbf);
    tree_kernel<<<BATCH / 4, 256, 0, stream>>>(Xbf, out);
}

// Round 9
// 191.261 us; speedup vs baseline: 1.0523x; 1.0523x over previous
//
#include <hip/hip_runtime.h>
#include <stdint.h>

// Problem constants
#define K_DIM   2048      // IN_DIM
#define NN      2047      // N_NODES
#define NPAD    2048      // padded node dim
#define BATCH   16384
#define ODIM    10
#define IOFF    (128 * 2048)   // +128 rows in elements

typedef __attribute__((ext_vector_type(8))) short  bf16x8;
typedef __attribute__((ext_vector_type(4))) float  f32x4;

static __device__ __forceinline__ unsigned short f2bf(float f) {
    union { float f; unsigned int u; } c; c.f = f;
    unsigned int u = c.u;
    return (unsigned short)((u + 0x7fffu + ((u >> 16) & 1u)) >> 16);
}
static __device__ __forceinline__ float bf2f(unsigned short h) {
    union { unsigned int u; float f; } c; c.u = ((unsigned int)h) << 16;
    return c.f;
}

// ---------------- fused fp32 -> bf16 conversion: in_x and padded W1 ----------------
__global__ __launch_bounds__(256) void cvt_all(const float* __restrict__ xs,
                                               const float* __restrict__ ws,
                                               unsigned short* __restrict__ dx,
                                               unsigned short* __restrict__ dw) {
    int b = blockIdx.x;
    union { unsigned short h[8]; uint4 v; } o;
    if (b < 16384) {
        int i = b * 256 + threadIdx.x;
        const float4* s = (const float4*)xs + (size_t)i * 2;
        float4 a = s[0], c = s[1];
        o.h[0] = f2bf(a.x); o.h[1] = f2bf(a.y); o.h[2] = f2bf(a.z); o.h[3] = f2bf(a.w);
        o.h[4] = f2bf(c.x); o.h[5] = f2bf(c.y); o.h[6] = f2bf(c.z); o.h[7] = f2bf(c.w);
        *((uint4*)dx + i) = o.v;
    } else {
        int i = (b - 16384) * 256 + threadIdx.x;
        size_t e = (size_t)i * 8;
        int row = (int)(e >> 11);
        if (row < NN) {
            const float4* s = (const float4*)(ws + e);
            float4 a = s[0], c = s[1];
            o.h[0] = f2bf(a.x); o.h[1] = f2bf(a.y); o.h[2] = f2bf(a.z); o.h[3] = f2bf(a.w);
            o.h[4] = f2bf(c.x); o.h[5] = f2bf(c.y); o.h[6] = f2bf(c.z); o.h[7] = f2bf(c.w);
        } else {
            o.v = make_uint4(0u, 0u, 0u, 0u);
        }
        *((uint4*)dw + i) = o.v;
    }
}

// ---------------- 256x256 bf16 MFMA GEMM, BK=32, 4 LDS buffers, 1 barrier/tile ----------------
// Per K-tile: [stage(T+3) | 12 ds_read | 32 MFMA | VM8 | BAR]. Stage distance 3 ensures the
// staged buffer is never being read (different buf mod 4); VM8+BAR pairs guarantee landing.
// LDS tile stored as [128 rowpairs][64 elems] with pcol = ((r&1)*4+lk) ^ ((r>>1)&7) XOR
// (conflict-free per quarter-wave, both stage and read sides).
__global__ __launch_bounds__(512, 1) void gemmK(const unsigned short* __restrict__ A,
                                                const unsigned short* __restrict__ B,
                                                const float* __restrict__ bias,
                                                unsigned short* __restrict__ X) {
    __shared__ char lds[131072];   // 4 bufs x (A 16KB + B 16KB)

    const int t0   = threadIdx.x;
    const int w    = t0 >> 6;
    const int lane = t0 & 63;
    const int wm = w >> 2, wn = w & 3;     // wave -> 128 rows x 64 cols
    const int lr = lane & 15, lk = lane >> 4;

    // XCD-aware swizzle: 512 wgs, 64 per XCD
    int bid = blockIdx.x;
    int swz = (bid & 7) * 64 + (bid >> 3);
    const int rowBase = (swz >> 3) * 256;  // 64 row-tiles
    const int colBase = (swz & 7) * 256;   // 8 col-tiles

    // ---- staging source (inverse-swizzled): thread covers (prow, pg); logical row
    // r = 2*prow + a, granule lk_s with (a*4+lk_s) = pg ^ (prow&7) ----
    const int pr  = w * 8 + (lane >> 3);           // prow for c=0 (0..63)
    const int q   = (lane & 7) ^ (pr & 7);
    const int a_s = (q >> 2) & 1, lk_s = q & 3;
    const unsigned short* sAa = A + (size_t)(rowBase + 2 * pr + a_s) * K_DIM + lk_s * 8;
    const unsigned short* sBa = B + (size_t)(colBase + 2 * pr + a_s) * K_DIM + lk_s * 8;

    // ---- read-side offsets: one base reg per matrix, frag index folds to imm ----
    const int pcol = (((lr & 1) << 2) + lk) ^ (lr >> 1);
    const int offA = (wm * 64 + (lr >> 1)) * 128 + pcol * 16;            // A region +0
    const int offB = 16384 + (wn * 32 + (lr >> 1)) * 128 + pcol * 16;    // B region +16KB

#define AS1 __attribute__((address_space(1)))
#define AS3 __attribute__((address_space(3)))
#define STG(src, dst) \
    __builtin_amdgcn_global_load_lds((const AS1 void*)(src), \
        (AS3 void*)(lds + (dst) + w * 1024), 16, 0, 0)
// stage K-tile (T+3) into buf (T+3)&3: A c0/c1, B c0/c1 (4 loads/thread)
#define STAGE4(T) do { \
    const int _o = (((T) + 3) & 3) * 32768; \
    const unsigned short* _a = sAa + ((T) + 3) * 32; \
    const unsigned short* _b = sBa + ((T) + 3) * 32; \
    STG(_a, _o); STG(_a + IOFF, _o + 8192); \
    STG(_b, _o + 16384); STG(_b + IOFF, _o + 24576); } while (0)

#define BAR()   __builtin_amdgcn_s_barrier()
#define VM0()   asm volatile("s_waitcnt vmcnt(0)" ::: "memory")
#define VM4()   asm volatile("s_waitcnt vmcnt(4)" ::: "memory")
#define VM8()   asm volatile("s_waitcnt vmcnt(8)" ::: "memory")
#define PRIO1() __builtin_amdgcn_s_setprio(1)
#define PRIO0() __builtin_amdgcn_s_setprio(0)

    f32x4 acc[8][4];
#pragma unroll
    for (int m = 0; m < 8; ++m)
#pragma unroll
        for (int n = 0; n < 4; ++n) acc[m][n] = (f32x4)0.f;

    bf16x8 aF[8], bF[4];

#define RDT(bo) do { \
    _Pragma("unroll") for (int n = 0; n < 4; ++n) \
        bF[n] = *(const bf16x8*)(lds + (bo) + offB + n * 1024); \
    _Pragma("unroll") for (int m = 0; m < 8; ++m) \
        aF[m] = *(const bf16x8*)(lds + (bo) + offA + m * 1024); } while (0)

#define MF32() do { \
    _Pragma("unroll") for (int m = 0; m < 8; ++m) \
    _Pragma("unroll") for (int n = 0; n < 4; ++n) \
        acc[m][n] = __builtin_amdgcn_mfma_f32_16x16x32_bf16(aF[m], bF[n], acc[m][n], 0, 0, 0); } while (0)

#define TILE_S(T) do { STAGE4(T); RDT(((T) & 3) * 32768); \
    PRIO1(); MF32(); PRIO0(); VM8(); BAR(); } while (0)
#define TILE_N(T, VMX) do { RDT(((T) & 3) * 32768); \
    PRIO1(); MF32(); PRIO0(); VMX; BAR(); } while (0)

    // ---- prologue: stage tiles 0,1,2 into bufs 0,1,2; VM8 drains buf0 ----
    STAGE4(-3); STAGE4(-2); STAGE4(-1);
    VM8(); BAR();

    // ---- main: 61 staged tiles + 3 drain tiles (stage T+3 <= 63, no wrap) ----
#pragma unroll 4
    for (int T = 0; T < 60; ++T) TILE_S(T);
    TILE_S(60);
    TILE_N(61, VM4());
    TILE_N(62, VM0());
    TILE_N(63, ((void)0));

    // ---- epilogue: + bias, store bf16. C/D: col = lane&15, row = lk*4 + reg ----
    float bb[4];
#pragma unroll
    for (int n = 0; n < 4; ++n) {
        int col = colBase + wn * 64 + n * 16 + lr;
        bb[n] = (col < NN) ? bias[col] : 0.f;
    }
#pragma unroll
    for (int m = 0; m < 8; ++m) {
        int rowb = rowBase + wm * 128 + m * 16 + lk * 4;
#pragma unroll
        for (int j = 0; j < 4; ++j) {
            unsigned short* xr = X + (size_t)(rowb + j) * NPAD + colBase + wn * 64 + lr;
#pragma unroll
            for (int n = 0; n < 4; ++n)
                xr[n * 16] = f2bf(acc[m][n][j] + bb[n]);
        }
    }
}

// ---------------- tree kernel: out[b,a] = S_abs[b] - min_{leaf≡a mod 10} pathPenalty ----------------
__global__ __launch_bounds__(256) void tree_kernel(const unsigned short* __restrict__ X,
                                                   float* __restrict__ out) {
    __shared__ float xs[4][2048];
    __shared__ float cm[4][64][ODIM];
    const int w    = threadIdx.x >> 6;
    const int lane = threadIdx.x & 63;
    const int row  = blockIdx.x * 4 + w;
    const unsigned short* xr = X + (size_t)row * NPAD;

#pragma unroll
    for (int i = 0; i < 4; ++i) {
        int base = i * 512 + lane * 8;
        uint4 v = *(const uint4*)(xr + base);
        const unsigned short* h = (const unsigned short*)&v;
#pragma unroll
        for (int j = 0; j < 8; ++j) xs[w][base + j] = bf2f(h[j]);
    }
    __syncthreads();

    float sabs = 0.f;
#pragma unroll
    for (int i = 0; i < 32; ++i) sabs += fabsf(xs[w][lane + i * 64]);
#pragma unroll
    for (int d = 1; d < 64; d <<= 1) sabs += __shfl_xor(sabs, d, 64);

    const int L = lane;
    float bp = 0.f;
#pragma unroll
    for (int l = 0; l <= 5; ++l) {
        float v = xs[w][(1 << l) - 1 + (L >> (6 - l))];
        bp += ((L >> (5 - l)) & 1) ? fmaxf(v, 0.f) : fmaxf(-v, 0.f);
    }
    float p2[2], p4[4], p8[8], p16[16], p32[32];
    {
        float v = xs[w][63 + L];
        p2[0] = bp + fmaxf(-v, 0.f);
        p2[1] = bp + fmaxf(v, 0.f);
    }
#pragma unroll
    for (int c = 0; c < 2; ++c) {
        float v = xs[w][127 + 2 * L + c];
        p4[2 * c]     = p2[c] + fmaxf(-v, 0.f);
        p4[2 * c + 1] = p2[c] + fmaxf(v, 0.f);
    }
#pragma unroll
    for (int c = 0; c < 4; ++c) {
        float v = xs[w][255 + 4 * L + c];
        p8[2 * c]     = p4[c] + fmaxf(-v, 0.f);
        p8[2 * c + 1] = p4[c] + fmaxf(v, 0.f);
    }
#pragma unroll
    for (int c = 0; c < 8; ++c) {
        float v = xs[w][511 + 8 * L + c];
        p16[2 * c]     = p8[c] + fmaxf(-v, 0.f);
        p16[2 * c + 1] = p8[c] + fmaxf(v, 0.f);
    }
#pragma unroll
    for (int c = 0; c < 16; ++c) {
        float v = xs[w][1023 + 16 * L + c];
        p32[2 * c]     = p16[c] + fmaxf(-v, 0.f);
        p32[2 * c + 1] = p16[c] + fmaxf(v, 0.f);
    }

    float m[ODIM];
#pragma unroll
    for (int r = 0; r < ODIM; ++r) m[r] = 1e30f;
#pragma unroll
    for (int tt = 0; tt < 32; ++tt) m[tt % ODIM] = fminf(m[tt % ODIM], p32[tt]);

    int base_mod = (L * 32) % ODIM;
#pragma unroll
    for (int r = 0; r < ODIM; ++r) {
        int a = base_mod + r; if (a >= ODIM) a -= ODIM;
        cm[w][L][a] = m[r];
    }
    __syncthreads();

    if (lane < ODIM) {
        float mn = 1e30f;
        for (int l2 = 0; l2 < 64; ++l2) mn = fminf(mn, cm[w][l2][lane]);
        out[(size_t)row * ODIM + lane] = sabs - mn;
    }
}

extern "C" void kernel_launch(void* const* d_in, const int* in_sizes, int n_in,
                              void* d_out, int out_size, void* d_ws, size_t ws_size,
                              hipStream_t stream) {
    const float* in_x = (const float*)d_in[0];
    const float* W1   = (const float*)d_in[1];
    const float* b1   = (const float*)d_in[2];

    unsigned short* Abf = (unsigned short*)d_ws;                      // 16384*2048 bf16
    unsigned short* Wbf = Abf + (size_t)BATCH * K_DIM;                // 2048*2048 bf16
    unsigned short* Xbf = Wbf + (size_t)NPAD * K_DIM;                 // 16384*2048 bf16
    float* out = (float*)d_out;

    cvt_all<<<18432, 256, 0, stream>>>(in_x, W1, Abf, Wbf);
    gemmK<<<512, 512, 0, stream>>>(Abf, Wbf, b1, Xbf);
    tree_kernel<<<BATCH / 4, 256, 0, stream>>>(Xbf, out);
}